// Round 11
// baseline (1376.048 us; speedup 1.0000x reference)
//
#include <hip/hip_runtime.h>
#include <stdint.h>

// ResRnn: T=128 sequential steps of  h=|s@W1^T+b1|; s'=0.9*shift(s)+0.1*(h@W2^T+b2)
// Persistent kernel: 256 WGs (1/CU), 4 independent batch-groups of 64 WGs,
// bf16 weights resident in VGPRs as MFMA B-frags.
// R6 protocol: per-chunk monotone gen flags, tid0 store AFTER __syncthreads.
// R14 (1632us): plain global_load_dwordx4 sc1 loads + counted vmcnt pipeline.
// R15 (1068us): K-tiled slab layouts (fully-used 128B lines).
// R16 (neutral): depth-4 pipeline -> NOT concurrency-limited; MALL read path
//     saturated at ~7.6TB/s serving 32MB/phase. Lever = traffic reduction.
// R17 (this round): XCD-LOCAL MIRROR READS.
//     Within a group all chunks read IDENTICAL operand data, and each XCD
//     hosts 32 WGs of one group (bid&3 aliases XCD&3) -> ~half of each wave's
//     producers are same-XCD. Producers now write exchanged data TWICE:
//     sc1 copy (MALL, for remote consumers — proven path) + PLAIN store to a
//     mirror buffer (dirty local L2; evictions write back to MALL, so local
//     sc0 reads are fresh resident-or-not). Consumers classify each producer
//     at runtime via a published XCC_ID table (s_getreg, m09): same-XCD ->
//     sc0 mirror read (L2 ~34.5TB/s agg); else sc1 (unchanged). Classification
//     is wave-uniform per load (producer chunk = 16w+4b+i, lane-independent);
//     branch via readfirstlane scalar masks -> exactly 1 VMEM per arm, vmcnt
//     thresholds intact. Startup verdict (bid0 histograms table; any anomaly
//     -> all-sc1 fallback == R16 exactly) makes bad placement degrade to
//     NEUTRAL, never incorrect. Flags/waits/stores otherwise identical.

#define NSTEPS 128
#define NB 128
#define WID 2048
#define SS 1984   // recurrent state width (WIDTH - INPUT_SIZE)

typedef __attribute__((ext_vector_type(8))) short short8;
typedef __attribute__((ext_vector_type(4))) short short4v;
typedef __attribute__((ext_vector_type(4))) float f32x4;
typedef unsigned long long u64;

static __device__ __forceinline__ short f2bf(float f) {
  union { float f; unsigned u; } v; v.f = f;
  unsigned r = (v.u + 0x7fffu + ((v.u >> 16) & 1u)) >> 16;  // RNE
  return (short)r;
}

static __device__ __forceinline__ short8 pack8(f32x4 lo, f32x4 hi) {
  short8 r;
  r[0] = f2bf(lo[0]); r[1] = f2bf(lo[1]); r[2] = f2bf(lo[2]); r[3] = f2bf(lo[3]);
  r[4] = f2bf(hi[0]); r[5] = f2bf(hi[1]); r[6] = f2bf(hi[2]); r[7] = f2bf(hi[3]);
  return r;
}

// write-through store to the agent coherence point (LLC); does not dirty L2
static __device__ __forceinline__ void ast64(void* p, u64 v) {
  __hip_atomic_store((u64*)p, v, __ATOMIC_RELAXED, __HIP_MEMORY_SCOPE_AGENT);
}
// LLC-direct coherent flag load
static __device__ __forceinline__ unsigned ald32(const unsigned* p) {
  return __hip_atomic_load(p, __ATOMIC_RELAXED, __HIP_MEMORY_SCOPE_AGENT);
}

// 16B agent-coherent load (sc1 = bypass L1/L2, read MALL). No waitcnt inside.
#define LLCLD(d, a) \
  asm volatile("global_load_dwordx4 %0, %1, off sc1" : "=&v"(d) : "v"(a))
// counted vmem wait + scheduler fence (rule #18)
#define VMW(n) do { \
    asm volatile("s_waitcnt vmcnt(" #n ")" ::: "memory"); \
    __builtin_amdgcn_sched_barrier(0); \
  } while (0)

// classified load: same-XCD producer -> sc0 mirror read (L1-bypass, L2-hit);
// remote -> sc1 MALL read. msk is a readfirstlane'd SCALAR -> uniform branch,
// exactly one VMEM instruction either way (vmcnt thresholds preserved).
#define CLD(d, gaddr, maddr, bit, msk) do {                                   \
    if ((msk) & (1u << (bit))) {                                              \
      asm volatile("global_load_dwordx4 %0, %1, off sc0"                      \
                   : "=&v"(d) : "v"(maddr));                                  \
    } else {                                                                  \
      asm volatile("global_load_dwordx4 %0, %1, off sc1"                      \
                   : "=&v"(d) : "v"(gaddr));                                  \
    }                                                                         \
  } while (0)

// ---- phase-1 issue macros (literal b/i: static indexing + literal mask bits) ----
#define P1ISSUE(b, X) do {                                                    \
    if (kb == 0 && (b) == 0) {  /* ks 0,1 = x_t input; ks 2,3 = state slabs */ \
      const float* q0_ = inp + ((size_t)t * NB + m0) * 64 + q8;               \
      const float* q1_ = inp + ((size_t)t * NB + m1) * 64 + q8;               \
      X[0] = pack8(*(const f32x4*)q0_, *(const f32x4*)(q0_ + 4));             \
      X[1] = pack8(*(const f32x4*)q1_, *(const f32x4*)(q1_ + 4));             \
      X[2] = pack8(*(const f32x4*)(q0_ + 32), *(const f32x4*)(q0_ + 36));     \
      X[3] = pack8(*(const f32x4*)(q1_ + 32), *(const f32x4*)(q1_ + 36));     \
      const short* g_ = SbOld  + (size_t)slabL * 1024;                        \
      const short* l_ = SbMOld + (size_t)slabL * 1024;                        \
      CLD(X[4], (g_ + rowoff0),        (l_ + rowoff0),        2, m1s);        \
      CLD(X[5], (g_ + rowoff1),        (l_ + rowoff1),        2, m1s);        \
      CLD(X[6], (g_ + 4096 + rowoff0), (l_ + 4096 + rowoff0), 3, m1s);        \
      CLD(X[7], (g_ + 4096 + rowoff1), (l_ + 4096 + rowoff1), 3, m1s);        \
    } else {                                                                  \
      const size_t sb_ = (size_t)(kb / 8 + 16 * (b) - 8 + slabL) * 1024;      \
      const short* g_ = SbOld + sb_;  const short* l_ = SbMOld + sb_;         \
      CLD(X[0], (g_ + rowoff0),         (l_ + rowoff0),         4*(b)+0, m1s);\
      CLD(X[1], (g_ + rowoff1),         (l_ + rowoff1),         4*(b)+0, m1s);\
      CLD(X[2], (g_ + 4096 + rowoff0),  (l_ + 4096 + rowoff0),  4*(b)+1, m1s);\
      CLD(X[3], (g_ + 4096 + rowoff1),  (l_ + 4096 + rowoff1),  4*(b)+1, m1s);\
      CLD(X[4], (g_ + 8192 + rowoff0),  (l_ + 8192 + rowoff0),  4*(b)+2, m1s);\
      CLD(X[5], (g_ + 8192 + rowoff1),  (l_ + 8192 + rowoff1),  4*(b)+2, m1s);\
      CLD(X[6], (g_ + 12288 + rowoff0), (l_ + 12288 + rowoff0), 4*(b)+3, m1s);\
      CLD(X[7], (g_ + 12288 + rowoff1), (l_ + 12288 + rowoff1), 4*(b)+3, m1s);\
    }                                                                         \
  } while (0)

#define P1MFMA(b, X) do {                                                     \
    a00 = __builtin_amdgcn_mfma_f32_16x16x32_bf16(X[0], B1[4*(b)+0][0], a00, 0,0,0); \
    a01 = __builtin_amdgcn_mfma_f32_16x16x32_bf16(X[0], B1[4*(b)+0][1], a01, 0,0,0); \
    a10 = __builtin_amdgcn_mfma_f32_16x16x32_bf16(X[1], B1[4*(b)+0][0], a10, 0,0,0); \
    a11 = __builtin_amdgcn_mfma_f32_16x16x32_bf16(X[1], B1[4*(b)+0][1], a11, 0,0,0); \
    a00 = __builtin_amdgcn_mfma_f32_16x16x32_bf16(X[2], B1[4*(b)+1][0], a00, 0,0,0); \
    a01 = __builtin_amdgcn_mfma_f32_16x16x32_bf16(X[2], B1[4*(b)+1][1], a01, 0,0,0); \
    a10 = __builtin_amdgcn_mfma_f32_16x16x32_bf16(X[3], B1[4*(b)+1][0], a10, 0,0,0); \
    a11 = __builtin_amdgcn_mfma_f32_16x16x32_bf16(X[3], B1[4*(b)+1][1], a11, 0,0,0); \
    a00 = __builtin_amdgcn_mfma_f32_16x16x32_bf16(X[4], B1[4*(b)+2][0], a00, 0,0,0); \
    a01 = __builtin_amdgcn_mfma_f32_16x16x32_bf16(X[4], B1[4*(b)+2][1], a01, 0,0,0); \
    a10 = __builtin_amdgcn_mfma_f32_16x16x32_bf16(X[5], B1[4*(b)+2][0], a10, 0,0,0); \
    a11 = __builtin_amdgcn_mfma_f32_16x16x32_bf16(X[5], B1[4*(b)+2][1], a11, 0,0,0); \
    a00 = __builtin_amdgcn_mfma_f32_16x16x32_bf16(X[6], B1[4*(b)+3][0], a00, 0,0,0); \
    a01 = __builtin_amdgcn_mfma_f32_16x16x32_bf16(X[6], B1[4*(b)+3][1], a01, 0,0,0); \
    a10 = __builtin_amdgcn_mfma_f32_16x16x32_bf16(X[7], B1[4*(b)+3][0], a10, 0,0,0); \
    a11 = __builtin_amdgcn_mfma_f32_16x16x32_bf16(X[7], B1[4*(b)+3][1], a11, 0,0,0); \
  } while (0)

// phase-2: producer chunk = 16w+4b+i (wave-uniform), mask m2s
#define P2ISSUE(b, X) do {                                                    \
    const size_t hb_ = (size_t)(kb / 8 + 16 * (b) + slabL) * 1024;            \
    const short* g_ = hb + hb_;  const short* l_ = hbM + hb_;                 \
    CLD(X[0], (g_ + rowoff0),         (l_ + rowoff0),         4*(b)+0, m2s);  \
    CLD(X[1], (g_ + rowoff1),         (l_ + rowoff1),         4*(b)+0, m2s);  \
    CLD(X[2], (g_ + 4096 + rowoff0),  (l_ + 4096 + rowoff0),  4*(b)+1, m2s);  \
    CLD(X[3], (g_ + 4096 + rowoff1),  (l_ + 4096 + rowoff1),  4*(b)+1, m2s);  \
    CLD(X[4], (g_ + 8192 + rowoff0),  (l_ + 8192 + rowoff0),  4*(b)+2, m2s);  \
    CLD(X[5], (g_ + 8192 + rowoff1),  (l_ + 8192 + rowoff1),  4*(b)+2, m2s);  \
    CLD(X[6], (g_ + 12288 + rowoff0), (l_ + 12288 + rowoff0), 4*(b)+3, m2s);  \
    CLD(X[7], (g_ + 12288 + rowoff1), (l_ + 12288 + rowoff1), 4*(b)+3, m2s);  \
  } while (0)

#define P2MFMA(b, X) do {                                                     \
    c00 = __builtin_amdgcn_mfma_f32_16x16x32_bf16(X[0], B2[4*(b)+0][0], c00, 0,0,0); \
    c01 = __builtin_amdgcn_mfma_f32_16x16x32_bf16(X[0], B2[4*(b)+0][1], c01, 0,0,0); \
    c10 = __builtin_amdgcn_mfma_f32_16x16x32_bf16(X[1], B2[4*(b)+0][0], c10, 0,0,0); \
    c11 = __builtin_amdgcn_mfma_f32_16x16x32_bf16(X[1], B2[4*(b)+0][1], c11, 0,0,0); \
    c00 = __builtin_amdgcn_mfma_f32_16x16x32_bf16(X[2], B2[4*(b)+1][0], c00, 0,0,0); \
    c01 = __builtin_amdgcn_mfma_f32_16x16x32_bf16(X[2], B2[4*(b)+1][1], c01, 0,0,0); \
    c10 = __builtin_amdgcn_mfma_f32_16x16x32_bf16(X[3], B2[4*(b)+1][0], c10, 0,0,0); \
    c11 = __builtin_amdgcn_mfma_f32_16x16x32_bf16(X[3], B2[4*(b)+1][1], c11, 0,0,0); \
    c00 = __builtin_amdgcn_mfma_f32_16x16x32_bf16(X[4], B2[4*(b)+2][0], c00, 0,0,0); \
    c01 = __builtin_amdgcn_mfma_f32_16x16x32_bf16(X[4], B2[4*(b)+2][1], c01, 0,0,0); \
    c10 = __builtin_amdgcn_mfma_f32_16x16x32_bf16(X[5], B2[4*(b)+2][0], c10, 0,0,0); \
    c11 = __builtin_amdgcn_mfma_f32_16x16x32_bf16(X[5], B2[4*(b)+2][1], c11, 0,0,0); \
    c00 = __builtin_amdgcn_mfma_f32_16x16x32_bf16(X[6], B2[4*(b)+3][0], c00, 0,0,0); \
    c01 = __builtin_amdgcn_mfma_f32_16x16x32_bf16(X[6], B2[4*(b)+3][1], c01, 0,0,0); \
    c10 = __builtin_amdgcn_mfma_f32_16x16x32_bf16(X[7], B2[4*(b)+3][0], c10, 0,0,0); \
    c11 = __builtin_amdgcn_mfma_f32_16x16x32_bf16(X[7], B2[4*(b)+3][1], c11, 0,0,0); \
  } while (0)

__global__ __launch_bounds__(256, 1)
void resrnn_kernel(const float* __restrict__ inp, const float* __restrict__ W1,
                   const float* __restrict__ b1f, const float* __restrict__ W2,
                   const float* __restrict__ b2f, float* __restrict__ out,
                   unsigned char* __restrict__ ws)
{
  const int tid   = threadIdx.x;
  const int bid   = blockIdx.x;
  const int group = bid & 3;        // 4 independent batch groups (32 rows each)
  const int chunk = bid >> 2;       // 64 N-chunks of 32 cols
  const int mbase = group * 32;
  const int n0    = chunk * 32;
  const int wave  = tid >> 6;
  const int lane  = tid & 63;
  const int l15   = lane & 15;
  const int q8    = (lane >> 4) * 8;
  const int kb    = wave * 512;     // K split 4 ways across waves
  const int slabL = lane >> 4;      // tiled-read slab offset per lane quad

  // flags: 0..32768 (sgen/hgen). R17: xtab @32768 (256 u32), verdict @33792.
  unsigned* sgen = (unsigned*)(ws + group * 8192);
  unsigned* hgen = (unsigned*)(ws + group * 8192 + 4096);
  unsigned* xtab = (unsigned*)(ws + 32768);
  unsigned* verd = (unsigned*)(ws + 33792);
  // data base rebased to 36864; tiled: SfT[248][128][8]f32, SbT[248][128][8],
  // hbT[256][128][8] bf16; mirrors hbM / SbM0 / SbM1 (local-L2 copies).
  float* Sf0  = (float*)(ws + 36864);
  float* Sf1  = (float*)(ws + 36864 + 1015808);
  short* Sb0  = (short*)(ws + 36864 + 2031616);
  short* Sb1  = (short*)(ws + 36864 + 2539520);
  short* hb   = (short*)(ws + 36864 + 3047424);
  short* hbM  = (short*)(ws + 36864 + 3571712);
  short* SbM0 = (short*)(ws + 36864 + 4096000);
  short* SbM1 = (short*)(ws + 36864 + 4603904);

  __shared__ float red[4][16][65];  // +1 pad: conflict-free cross-wave reduce
  __shared__ unsigned hcnt[10];

  // ---- R17 startup: publish XCD id, bid0 verdict, classification masks ----
  unsigned xraw;
  asm("s_getreg_b32 %0, hwreg(HW_REG_XCC_ID)" : "=s"(xraw));
  const unsigned myx = xraw + 1u;   // published nonzero; raw>7 -> verdict 2
  if (tid == 0)
    __hip_atomic_store(xtab + bid, myx, __ATOMIC_RELAXED, __HIP_MEMORY_SCOPE_AGENT);
  if (bid == 0) {
    unsigned v;
    for (;;) { v = ald32(xtab + tid); if (v) break; __builtin_amdgcn_s_sleep(2); }
    if (tid < 10) hcnt[tid] = 0;
    __syncthreads();
    atomicAdd(&hcnt[v <= 8 ? v : 0], 1u);
    __syncthreads();
    if (tid == 0) {
      bool ok = (hcnt[0] == 0);
      for (int q = 1; q <= 8; ++q) if (hcnt[q] != 32) ok = false;
      __hip_atomic_store(verd, ok ? 1u : 2u, __ATOMIC_RELAXED, __HIP_MEMORY_SCOPE_AGENT);
    }
  }

  // ---- one-time: load & convert weight B-fragments into registers ----
  short8 B1[16][2], B2[16][2];
#pragma unroll
  for (int ks = 0; ks < 16; ++ks) {
#pragma unroll
    for (int nt = 0; nt < 2; ++nt) {
      const float* p1 = W1 + (size_t)(n0 + nt * 16 + l15) * WID + (kb + ks * 32 + q8);
      B1[ks][nt] = pack8(*(const f32x4*)p1, *(const f32x4*)(p1 + 4));
      const float* p2 = W2 + (size_t)(n0 + nt * 16 + l15) * WID + (kb + ks * 32 + q8);
      B2[ks][nt] = pack8(*(const f32x4*)p2, *(const f32x4*)(p2 + 4));
    }
  }

  // verdict + masks (producer chunk for load j of a phase = 16*wave + j)
  unsigned vd;
  for (;;) { vd = ald32(verd); if (vd) break; __builtin_amdgcn_s_sleep(2); }
  unsigned m1v = 0, m2v = 0;
  if (vd == 1) {
    for (int j = 0; j < 16; ++j) {
      const int p2c = 16 * wave + j;
      if (ald32(xtab + ((p2c << 2) | group)) == myx) m2v |= 1u << j;
      const int p1c = p2c - 2;
      if (p1c >= 0 && ald32(xtab + ((p1c << 2) | group)) == myx) m1v |= 1u << j;
    }
  }
  const unsigned m1s = __builtin_amdgcn_readfirstlane(m1v);
  const unsigned m2s = __builtin_amdgcn_readfirstlane(m2v);

  const int m0 = mbase + l15;        // A-frag rows (m-tile 0)
  const int m1 = mbase + 16 + l15;   // m-tile 1
  const int rowoff0 = (mbase + l15) * 8;        // shorts/floats into a slab
  const int rowoff1 = rowoff0 + 128;            // +16 rows

  // epilogue thread-remap: ml=(tid&63)>>1, nl=wave*8+(tid&1)*4 (bijection)
  const int ml   = (tid & 63) >> 1;
  const int nl   = ((tid >> 6) << 3) + ((tid & 1) << 2);
  const int mrow = mbase + ml;
  const int c0   = n0 + nl;
  const size_t toff = (size_t)(n0 / 8 + wave) * 1024 + (size_t)mrow * 8
                    + (size_t)((tid & 1) << 2);

  const f32x4 b1r = *(const f32x4*)(b1f + c0);
  const f32x4 b2r = *(const f32x4*)(b2f + c0);

  // phase-1 wait: lanes 0..15 poll the 16 A-operand producers; lane 16 polls
  // chunk-2 (covers the hoisted fp32 prev read).
  const int p1pc = 16 * wave + l15 - 2;
  const bool p1needA = (lane < 16) && (p1pc >= 0);
  const bool p1needB = (lane == 16) && (chunk >= 2);
  const unsigned* p1fp =
      p1needA ? (sgen + p1pc * 16)
              : (sgen + (chunk >= 2 ? chunk - 2 : 0) * 16);
  const unsigned* p2fp = hgen + (16 * wave + l15) * 16;

  short8 xa[8], xb[8], xc[8], xd[8];   // 4-deep in-flight operand blocks

#pragma unroll 1
  for (int t = 0; t < NSTEPS; ++t) {
    const float* SfOld  = (t & 1) ? Sf1 : Sf0;
    float*       SfNew  = (t & 1) ? Sf0 : Sf1;
    const short* SbOld  = (t & 1) ? Sb1 : Sb0;
    short*       SbNew  = (t & 1) ? Sb0 : Sb1;
    const short* SbMOld = (t & 1) ? SbM1 : SbM0;
    short*       SbMNew = (t & 1) ? SbM0 : SbM1;

    // ================= phase 1: u = s_in @ W1^T ; h = |u + b1| =================
    f32x4 a00{}, a01{}, a10{}, a11{};
    f32x4 prevv;
    if (t == 0) {
      prevv = (c0 < 64) ? *(const f32x4*)(inp + (size_t)mrow * 64 + c0)
                        : f32x4{0.f, 0.f, 0.f, 0.f};
      if (kb == 0) {
        const float* q0_ = inp + (size_t)m0 * 64 + q8;
        const float* q1_ = inp + (size_t)m1 * 64 + q8;
        short8 x0 = pack8(*(const f32x4*)q0_, *(const f32x4*)(q0_ + 4));
        short8 x1 = pack8(*(const f32x4*)q1_, *(const f32x4*)(q1_ + 4));
        short8 x2 = pack8(*(const f32x4*)(q0_ + 32), *(const f32x4*)(q0_ + 36));
        short8 x3 = pack8(*(const f32x4*)(q1_ + 32), *(const f32x4*)(q1_ + 36));
        a00 = __builtin_amdgcn_mfma_f32_16x16x32_bf16(x0, B1[0][0], a00, 0, 0, 0);
        a01 = __builtin_amdgcn_mfma_f32_16x16x32_bf16(x0, B1[0][1], a01, 0, 0, 0);
        a10 = __builtin_amdgcn_mfma_f32_16x16x32_bf16(x1, B1[0][0], a10, 0, 0, 0);
        a11 = __builtin_amdgcn_mfma_f32_16x16x32_bf16(x1, B1[0][1], a11, 0, 0, 0);
        a00 = __builtin_amdgcn_mfma_f32_16x16x32_bf16(x2, B1[1][0], a00, 0, 0, 0);
        a01 = __builtin_amdgcn_mfma_f32_16x16x32_bf16(x2, B1[1][1], a01, 0, 0, 0);
        a10 = __builtin_amdgcn_mfma_f32_16x16x32_bf16(x3, B1[1][0], a10, 0, 0, 0);
        a11 = __builtin_amdgcn_mfma_f32_16x16x32_bf16(x3, B1[1][1], a11, 0, 0, 0);
      }
    } else {
      {  // one sticky wait for all of this wave's producers (before any issue)
        const unsigned tgt = (unsigned)t;
        bool pend = p1needA || p1needB;
        for (;;) {
          if (pend && ald32(p1fp) >= tgt) pend = false;
          if (__ballot(pend) == 0ull) break;
        }
      }
      if (chunk < 2) {
        prevv = *(const f32x4*)(inp + ((size_t)t * NB + mrow) * 64 + c0);
        P1ISSUE(0, xa); P1ISSUE(1, xb); P1ISSUE(2, xc); P1ISSUE(3, xd);
        VMW(24); P1MFMA(0, xa);
        VMW(16); P1MFMA(1, xb);
        VMW(8);  P1MFMA(2, xc);
        VMW(0);  P1MFMA(3, xd);
      } else {
        P1ISSUE(0, xa); P1ISSUE(1, xb); P1ISSUE(2, xc); P1ISSUE(3, xd);
        LLCLD(prevv, (SfOld + toff - 8192));   // sc1 always (unclassified)
        VMW(25); P1MFMA(0, xa);
        VMW(17); P1MFMA(1, xb);
        VMW(9);  P1MFMA(2, xc);
        VMW(1);  P1MFMA(3, xd);
      }
    }
#pragma unroll
    for (int r = 0; r < 4; ++r) {            // ridx = mt*8 + nt*4 + r
      red[wave][r][lane]      = a00[r];
      red[wave][4 + r][lane]  = a01[r];
      red[wave][8 + r][lane]  = a10[r];
      red[wave][12 + r][lane] = a11[r];
    }
    __syncthreads();
    {
      short4v hv;
#pragma unroll
      for (int j = 0; j < 4; ++j) {
        const int nn   = nl + j;
        const int lidx = ((ml >> 2) & 3) * 16 + (nn & 15);
        const int ridx = (ml >> 4) * 8 + (nn >> 4) * 4 + (ml & 3);
        float s = red[0][ridx][lidx] + red[1][ridx][lidx]
                + red[2][ridx][lidx] + red[3][ridx][lidx];
        s += b1r[j];
        hv[j] = f2bf(fabsf(s));
      }
      union { short4v s; u64 u; } hu; hu.s = hv;
      ast64(hb + toff, hu.u);            // sc1 copy (remote consumers)
      *(u64*)(hbM + toff) = hu.u;        // mirror copy (local L2 consumers)
    }
    __syncthreads();   // all 4 waves' stores drained (vmcnt0) before signal
    if (tid == 0)
      __hip_atomic_store(hgen + chunk * 16, (unsigned)t + 1,
                         __ATOMIC_RELAXED, __HIP_MEMORY_SCOPE_AGENT);

    // ================= phase 2: g = h @ W2^T ; state update =================
    f32x4 c00{}, c01{}, c10{}, c11{};
    {
      {  // one sticky wait for this wave's 16 h-producers
        const unsigned tgt = (unsigned)t + 1;
        bool pend = (lane < 16);
        for (;;) {
          if (pend && ald32(p2fp) >= tgt) pend = false;
          if (__ballot(pend) == 0ull) break;
        }
      }
      P2ISSUE(0, xa); P2ISSUE(1, xb); P2ISSUE(2, xc); P2ISSUE(3, xd);
      VMW(24); P2MFMA(0, xa);
      VMW(16); P2MFMA(1, xb);
      VMW(8);  P2MFMA(2, xc);
      VMW(0);  P2MFMA(3, xd);
    }
#pragma unroll
    for (int r = 0; r < 4; ++r) {
      red[wave][r][lane]      = c00[r];
      red[wave][4 + r][lane]  = c01[r];
      red[wave][8 + r][lane]  = c10[r];
      red[wave][12 + r][lane] = c11[r];
    }
    __syncthreads();
    if (t < NSTEPS - 1) {
      if (n0 < SS) {   // cols >= SS are dropped by the shift (except final step)
        f32x4 gv;
#pragma unroll
        for (int j = 0; j < 4; ++j) {
          const int nn   = nl + j;
          const int lidx = ((ml >> 2) & 3) * 16 + (nn & 15);
          const int ridx = (ml >> 4) * 8 + (nn >> 4) * 4 + (ml & 3);
          gv[j] = red[0][ridx][lidx] + red[1][ridx][lidx]
                + red[2][ridx][lidx] + red[3][ridx][lidx] + b2r[j];
        }
        f32x4 sv; short4v sb;
#pragma unroll
        for (int j = 0; j < 4; ++j) {
          float vv = 0.9f * prevv[j] + 0.1f * gv[j];
          sv[j] = vv; sb[j] = f2bf(vv);
        }
        union { f32x4 f; u64 u[2]; } sfu; sfu.f = sv;
        float* pf = SfNew + toff;
        ast64(pf, sfu.u[0]);
        ast64(pf + 2, sfu.u[1]);
        union { short4v s; u64 u; } sbu; sbu.s = sb;
        ast64(SbNew + toff, sbu.u);        // sc1 copy
        *(u64*)(SbMNew + toff) = sbu.u;    // mirror copy
      }
      __syncthreads();   // all 4 waves' S stores drained before signal
      if (tid == 0 && chunk < 62)
        __hip_atomic_store(sgen + chunk * 16, (unsigned)t + 1,
                           __ATOMIC_RELAXED, __HIP_MEMORY_SCOPE_AGENT);
    } else {
      // final step: out[m, :] = 0.9*s_in[m, 1984+o] + 0.1*(g+b2)[m, 1984+o]
      if (n0 >= SS) {
        f32x4 gv;
#pragma unroll
        for (int j = 0; j < 4; ++j) {
          const int nn   = nl + j;
          const int lidx = ((ml >> 2) & 3) * 16 + (nn & 15);
          const int ridx = (ml >> 4) * 8 + (nn >> 4) * 4 + (ml & 3);
          gv[j] = red[0][ridx][lidx] + red[1][ridx][lidx]
                + red[2][ridx][lidx] + red[3][ridx][lidx] + b2r[j];
        }
        f32x4 ov;
#pragma unroll
        for (int j = 0; j < 4; ++j) ov[j] = 0.9f * prevv[j] + 0.1f * gv[j];
        *(f32x4*)(out + (size_t)mrow * 64 + (c0 - SS)) = ov;
      }
    }
  }
}

extern "C" void kernel_launch(void* const* d_in, const int* in_sizes, int n_in,
                              void* d_out, int out_size, void* d_ws, size_t ws_size,
                              hipStream_t stream)
{
  (void)in_sizes; (void)n_in; (void)out_size; (void)ws_size;
  const float* inp = (const float*)d_in[0];
  const float* W1  = (const float*)d_in[1];
  const float* b1  = (const float*)d_in[2];
  const float* W2  = (const float*)d_in[3];
  const float* b2  = (const float*)d_in[4];
  float* out = (float*)d_out;

  // zero flags + xcd table + verdict (ws re-poisoned before every launch)
  hipMemsetAsync(d_ws, 0, 34048, stream);
  resrnn_kernel<<<dim3(256), dim3(256), 0, stream>>>(
      inp, W1, b1, W2, b2, out, (unsigned char*)d_ws);
}

// Round 12
// 1087.811 us; speedup vs baseline: 1.2650x; 1.2650x over previous
//
#include <hip/hip_runtime.h>
#include <stdint.h>

// ResRnn: T=128 sequential steps of  h=|s@W1^T+b1|; s'=0.9*shift(s)+0.1*(h@W2^T+b2)
// Persistent kernel: 256 WGs (1/CU), 4 independent batch-groups of 64 WGs,
// bf16 weights resident in VGPRs as MFMA B-frags.
// R6 protocol: per-chunk monotone gen flags, tid0 store AFTER __syncthreads.
// R14 (1632us): plain global_load_dwordx4 sc1 loads + counted vmcnt pipeline.
// R15 (1068us): K-tiled slab layouts (fully-used 128B lines).
// R16 (neutral): depth-4 -> MALL read path saturated ~7.6TB/s, not
//     concurrency-limited. Lever = traffic reduction.
// R17 REVERTED (mirror buffers: 1376us. FETCH 306->260 proved sc0 local-L2
//     hits AND verdict=1 (32 WGs of one group per XCD confirmed), but the
//     double-write evicted ~1MB/step dirty to HBM (WRITE +124MB) and lost
//     more than locality gained. Mechanism wrong, diagnosis right.)
// R18 (this round): SC0 READS OF THE MAIN BUFFER for same-XCD producers.
//     No mirrors, no double stores — store path is exactly R16's single sc1
//     write-through. Same-XCD consumers read the SAME address with sc0
//     (allocate in the shared local L2): first read fills fresh from MALL;
//     later generations either hit an updated line (sc1 store = write-
//     through-update) or miss+refill fresh (invalidate-on-store). Both
//     correct; only "store skips resident stale line" fails -> detectable,
//     revert. prevv (producer chunk-2, same parity) is also local under
//     verdict=1 -> sc0. Verdict=2 fallback = all-sc1 = R16 exactly.
//     Masks are readfirstlane'd scalars -> uniform branch, 1 VMEM per arm,
//     counted-vmcnt thresholds intact.

#define NSTEPS 128
#define NB 128
#define WID 2048
#define SS 1984   // recurrent state width (WIDTH - INPUT_SIZE)

typedef __attribute__((ext_vector_type(8))) short short8;
typedef __attribute__((ext_vector_type(4))) short short4v;
typedef __attribute__((ext_vector_type(4))) float f32x4;
typedef unsigned long long u64;

static __device__ __forceinline__ short f2bf(float f) {
  union { float f; unsigned u; } v; v.f = f;
  unsigned r = (v.u + 0x7fffu + ((v.u >> 16) & 1u)) >> 16;  // RNE
  return (short)r;
}

static __device__ __forceinline__ short8 pack8(f32x4 lo, f32x4 hi) {
  short8 r;
  r[0] = f2bf(lo[0]); r[1] = f2bf(lo[1]); r[2] = f2bf(lo[2]); r[3] = f2bf(lo[3]);
  r[4] = f2bf(hi[0]); r[5] = f2bf(hi[1]); r[6] = f2bf(hi[2]); r[7] = f2bf(hi[3]);
  return r;
}

// write-through store to the agent coherence point (LLC); single copy (R16 path)
static __device__ __forceinline__ void ast64(void* p, u64 v) {
  __hip_atomic_store((u64*)p, v, __ATOMIC_RELAXED, __HIP_MEMORY_SCOPE_AGENT);
}
// LLC-direct coherent flag load
static __device__ __forceinline__ unsigned ald32(const unsigned* p) {
  return __hip_atomic_load(p, __ATOMIC_RELAXED, __HIP_MEMORY_SCOPE_AGENT);
}

// 16B agent-coherent load (sc1 = bypass L1/L2, read MALL). No waitcnt inside.
#define LLCLD(d, a) \
  asm volatile("global_load_dwordx4 %0, %1, off sc1" : "=&v"(d) : "v"(a))
// counted vmem wait + scheduler fence (rule #18)
#define VMW(n) do { \
    asm volatile("s_waitcnt vmcnt(" #n ")" ::: "memory"); \
    __builtin_amdgcn_sched_barrier(0); \
  } while (0)

// classified load of the SAME address: same-XCD producer -> sc0 (allocate in
// shared local L2; fresh by write-through or miss-refill); remote -> sc1.
// msk is a readfirstlane'd SCALAR -> uniform branch, one VMEM either way.
#define CLD(d, a, bit, msk) do {                                              \
    if ((msk) & (1u << (bit))) {                                              \
      asm volatile("global_load_dwordx4 %0, %1, off sc0" : "=&v"(d) : "v"(a));\
    } else {                                                                  \
      asm volatile("global_load_dwordx4 %0, %1, off sc1" : "=&v"(d) : "v"(a));\
    }                                                                         \
  } while (0)

// ---- phase-1 issue macros (literal b: static indexing + literal mask bits) --
// producer chunk for phase-1 load j = 16*wave + j - 2 (j=0,1 -> input)
#define P1ISSUE(b, X) do {                                                    \
    if (kb == 0 && (b) == 0) {  /* ks 0,1 = x_t input; ks 2,3 = state slabs */ \
      const float* q0_ = inp + ((size_t)t * NB + m0) * 64 + q8;               \
      const float* q1_ = inp + ((size_t)t * NB + m1) * 64 + q8;               \
      X[0] = pack8(*(const f32x4*)q0_, *(const f32x4*)(q0_ + 4));             \
      X[1] = pack8(*(const f32x4*)q1_, *(const f32x4*)(q1_ + 4));             \
      X[2] = pack8(*(const f32x4*)(q0_ + 32), *(const f32x4*)(q0_ + 36));     \
      X[3] = pack8(*(const f32x4*)(q1_ + 32), *(const f32x4*)(q1_ + 36));     \
      const short* s_ = SbOld + (size_t)slabL * 1024;                         \
      CLD(X[4], (s_ + rowoff0),        2, m1s);                               \
      CLD(X[5], (s_ + rowoff1),        2, m1s);                               \
      CLD(X[6], (s_ + 4096 + rowoff0), 3, m1s);                               \
      CLD(X[7], (s_ + 4096 + rowoff1), 3, m1s);                               \
    } else {                                                                  \
      const short* s_ = SbOld + (size_t)(kb / 8 + 16 * (b) - 8 + slabL) * 1024; \
      CLD(X[0], (s_ + rowoff0),         4*(b)+0, m1s);                        \
      CLD(X[1], (s_ + rowoff1),         4*(b)+0, m1s);                        \
      CLD(X[2], (s_ + 4096 + rowoff0),  4*(b)+1, m1s);                        \
      CLD(X[3], (s_ + 4096 + rowoff1),  4*(b)+1, m1s);                        \
      CLD(X[4], (s_ + 8192 + rowoff0),  4*(b)+2, m1s);                        \
      CLD(X[5], (s_ + 8192 + rowoff1),  4*(b)+2, m1s);                        \
      CLD(X[6], (s_ + 12288 + rowoff0), 4*(b)+3, m1s);                        \
      CLD(X[7], (s_ + 12288 + rowoff1), 4*(b)+3, m1s);                        \
    }                                                                         \
  } while (0)

#define P1MFMA(b, X) do {                                                     \
    a00 = __builtin_amdgcn_mfma_f32_16x16x32_bf16(X[0], B1[4*(b)+0][0], a00, 0,0,0); \
    a01 = __builtin_amdgcn_mfma_f32_16x16x32_bf16(X[0], B1[4*(b)+0][1], a01, 0,0,0); \
    a10 = __builtin_amdgcn_mfma_f32_16x16x32_bf16(X[1], B1[4*(b)+0][0], a10, 0,0,0); \
    a11 = __builtin_amdgcn_mfma_f32_16x16x32_bf16(X[1], B1[4*(b)+0][1], a11, 0,0,0); \
    a00 = __builtin_amdgcn_mfma_f32_16x16x32_bf16(X[2], B1[4*(b)+1][0], a00, 0,0,0); \
    a01 = __builtin_amdgcn_mfma_f32_16x16x32_bf16(X[2], B1[4*(b)+1][1], a01, 0,0,0); \
    a10 = __builtin_amdgcn_mfma_f32_16x16x32_bf16(X[3], B1[4*(b)+1][0], a10, 0,0,0); \
    a11 = __builtin_amdgcn_mfma_f32_16x16x32_bf16(X[3], B1[4*(b)+1][1], a11, 0,0,0); \
    a00 = __builtin_amdgcn_mfma_f32_16x16x32_bf16(X[4], B1[4*(b)+2][0], a00, 0,0,0); \
    a01 = __builtin_amdgcn_mfma_f32_16x16x32_bf16(X[4], B1[4*(b)+2][1], a01, 0,0,0); \
    a10 = __builtin_amdgcn_mfma_f32_16x16x32_bf16(X[5], B1[4*(b)+2][0], a10, 0,0,0); \
    a11 = __builtin_amdgcn_mfma_f32_16x16x32_bf16(X[5], B1[4*(b)+2][1], a11, 0,0,0); \
    a00 = __builtin_amdgcn_mfma_f32_16x16x32_bf16(X[6], B1[4*(b)+3][0], a00, 0,0,0); \
    a01 = __builtin_amdgcn_mfma_f32_16x16x32_bf16(X[6], B1[4*(b)+3][1], a01, 0,0,0); \
    a10 = __builtin_amdgcn_mfma_f32_16x16x32_bf16(X[7], B1[4*(b)+3][0], a10, 0,0,0); \
    a11 = __builtin_amdgcn_mfma_f32_16x16x32_bf16(X[7], B1[4*(b)+3][1], a11, 0,0,0); \
  } while (0)

// phase-2: producer chunk = 16w+4b+i (wave-uniform), mask m2s
#define P2ISSUE(b, X) do {                                                    \
    const short* h_ = hb + (size_t)(kb / 8 + 16 * (b) + slabL) * 1024;        \
    CLD(X[0], (h_ + rowoff0),         4*(b)+0, m2s);                          \
    CLD(X[1], (h_ + rowoff1),         4*(b)+0, m2s);                          \
    CLD(X[2], (h_ + 4096 + rowoff0),  4*(b)+1, m2s);                          \
    CLD(X[3], (h_ + 4096 + rowoff1),  4*(b)+1, m2s);                          \
    CLD(X[4], (h_ + 8192 + rowoff0),  4*(b)+2, m2s);                          \
    CLD(X[5], (h_ + 8192 + rowoff1),  4*(b)+2, m2s);                          \
    CLD(X[6], (h_ + 12288 + rowoff0), 4*(b)+3, m2s);                          \
    CLD(X[7], (h_ + 12288 + rowoff1), 4*(b)+3, m2s);                          \
  } while (0)

#define P2MFMA(b, X) do {                                                     \
    c00 = __builtin_amdgcn_mfma_f32_16x16x32_bf16(X[0], B2[4*(b)+0][0], c00, 0,0,0); \
    c01 = __builtin_amdgcn_mfma_f32_16x16x32_bf16(X[0], B2[4*(b)+0][1], c01, 0,0,0); \
    c10 = __builtin_amdgcn_mfma_f32_16x16x32_bf16(X[1], B2[4*(b)+0][0], c10, 0,0,0); \
    c11 = __builtin_amdgcn_mfma_f32_16x16x32_bf16(X[1], B2[4*(b)+0][1], c11, 0,0,0); \
    c00 = __builtin_amdgcn_mfma_f32_16x16x32_bf16(X[2], B2[4*(b)+1][0], c00, 0,0,0); \
    c01 = __builtin_amdgcn_mfma_f32_16x16x32_bf16(X[2], B2[4*(b)+1][1], c01, 0,0,0); \
    c10 = __builtin_amdgcn_mfma_f32_16x16x32_bf16(X[3], B2[4*(b)+1][0], c10, 0,0,0); \
    c11 = __builtin_amdgcn_mfma_f32_16x16x32_bf16(X[3], B2[4*(b)+1][1], c11, 0,0,0); \
    c00 = __builtin_amdgcn_mfma_f32_16x16x32_bf16(X[4], B2[4*(b)+2][0], c00, 0,0,0); \
    c01 = __builtin_amdgcn_mfma_f32_16x16x32_bf16(X[4], B2[4*(b)+2][1], c01, 0,0,0); \
    c10 = __builtin_amdgcn_mfma_f32_16x16x32_bf16(X[5], B2[4*(b)+2][0], c10, 0,0,0); \
    c11 = __builtin_amdgcn_mfma_f32_16x16x32_bf16(X[5], B2[4*(b)+2][1], c11, 0,0,0); \
    c00 = __builtin_amdgcn_mfma_f32_16x16x32_bf16(X[6], B2[4*(b)+3][0], c00, 0,0,0); \
    c01 = __builtin_amdgcn_mfma_f32_16x16x32_bf16(X[6], B2[4*(b)+3][1], c01, 0,0,0); \
    c10 = __builtin_amdgcn_mfma_f32_16x16x32_bf16(X[7], B2[4*(b)+3][0], c10, 0,0,0); \
    c11 = __builtin_amdgcn_mfma_f32_16x16x32_bf16(X[7], B2[4*(b)+3][1], c11, 0,0,0); \
  } while (0)

__global__ __launch_bounds__(256, 1)
void resrnn_kernel(const float* __restrict__ inp, const float* __restrict__ W1,
                   const float* __restrict__ b1f, const float* __restrict__ W2,
                   const float* __restrict__ b2f, float* __restrict__ out,
                   unsigned char* __restrict__ ws)
{
  const int tid   = threadIdx.x;
  const int bid   = blockIdx.x;
  const int group = bid & 3;        // 4 independent batch groups (32 rows each)
  const int chunk = bid >> 2;       // 64 N-chunks of 32 cols
  const int mbase = group * 32;
  const int n0    = chunk * 32;
  const int wave  = tid >> 6;
  const int lane  = tid & 63;
  const int l15   = lane & 15;
  const int q8    = (lane >> 4) * 8;
  const int kb    = wave * 512;     // K split 4 ways across waves
  const int slabL = lane >> 4;      // tiled-read slab offset per lane quad

  // flags: 0..32768 (sgen/hgen). xtab @32768 (256 u32), verdict @33792.
  unsigned* sgen = (unsigned*)(ws + group * 8192);
  unsigned* hgen = (unsigned*)(ws + group * 8192 + 4096);
  unsigned* xtab = (unsigned*)(ws + 32768);
  unsigned* verd = (unsigned*)(ws + 33792);
  // tiled buffers (NO mirrors): SfT[248][128][8]f32, SbT[248][128][8] bf16,
  // hbT[256][128][8] bf16
  float* Sf0  = (float*)(ws + 36864);
  float* Sf1  = (float*)(ws + 36864 + 1015808);
  short* Sb0  = (short*)(ws + 36864 + 2031616);
  short* Sb1  = (short*)(ws + 36864 + 2539520);
  short* hb   = (short*)(ws + 36864 + 3047424);

  __shared__ float red[4][16][65];  // +1 pad: conflict-free cross-wave reduce
  __shared__ unsigned hcnt[10];

  // ---- startup: publish XCD id, bid0 verdict, classification masks ----
  unsigned xraw;
  asm("s_getreg_b32 %0, hwreg(HW_REG_XCC_ID)" : "=s"(xraw));
  const unsigned myx = xraw + 1u;   // published nonzero; raw>7 -> verdict 2
  if (tid == 0)
    __hip_atomic_store(xtab + bid, myx, __ATOMIC_RELAXED, __HIP_MEMORY_SCOPE_AGENT);
  if (bid == 0) {
    unsigned v;
    for (;;) { v = ald32(xtab + tid); if (v) break; __builtin_amdgcn_s_sleep(2); }
    if (tid < 10) hcnt[tid] = 0;
    __syncthreads();
    atomicAdd(&hcnt[v <= 8 ? v : 0], 1u);
    __syncthreads();
    if (tid == 0) {
      bool ok = (hcnt[0] == 0);
      for (int q = 1; q <= 8; ++q) if (hcnt[q] != 32) ok = false;
      __hip_atomic_store(verd, ok ? 1u : 2u, __ATOMIC_RELAXED, __HIP_MEMORY_SCOPE_AGENT);
    }
  }

  // ---- one-time: load & convert weight B-fragments into registers ----
  short8 B1[16][2], B2[16][2];
#pragma unroll
  for (int ks = 0; ks < 16; ++ks) {
#pragma unroll
    for (int nt = 0; nt < 2; ++nt) {
      const float* p1 = W1 + (size_t)(n0 + nt * 16 + l15) * WID + (kb + ks * 32 + q8);
      B1[ks][nt] = pack8(*(const f32x4*)p1, *(const f32x4*)(p1 + 4));
      const float* p2 = W2 + (size_t)(n0 + nt * 16 + l15) * WID + (kb + ks * 32 + q8);
      B2[ks][nt] = pack8(*(const f32x4*)p2, *(const f32x4*)(p2 + 4));
    }
  }

  // verdict + masks (producer chunk for load j of a phase = 16*wave + j [-2 p1])
  unsigned vd;
  for (;;) { vd = ald32(verd); if (vd) break; __builtin_amdgcn_s_sleep(2); }
  unsigned m1v = 0, m2v = 0;
  if (vd == 1) {
    for (int j = 0; j < 16; ++j) {
      const int p2c = 16 * wave + j;
      if (ald32(xtab + ((p2c << 2) | group)) == myx) m2v |= 1u << j;
      const int p1c = p2c - 2;
      if (p1c >= 0 && ald32(xtab + ((p1c << 2) | group)) == myx) m1v |= 1u << j;
    }
  }
  const unsigned m1s = __builtin_amdgcn_readfirstlane(m1v);
  const unsigned m2s = __builtin_amdgcn_readfirstlane(m2v);
  // prevv producer = chunk-2 (same parity) -> local whenever verdict==1
  const bool locPrev = (__builtin_amdgcn_readfirstlane(vd) == 1u);

  const int m0 = mbase + l15;        // A-frag rows (m-tile 0)
  const int m1 = mbase + 16 + l15;   // m-tile 1
  const int rowoff0 = (mbase + l15) * 8;        // shorts/floats into a slab
  const int rowoff1 = rowoff0 + 128;            // +16 rows

  // epilogue thread-remap: ml=(tid&63)>>1, nl=wave*8+(tid&1)*4 (bijection)
  const int ml   = (tid & 63) >> 1;
  const int nl   = ((tid >> 6) << 3) + ((tid & 1) << 2);
  const int mrow = mbase + ml;
  const int c0   = n0 + nl;
  const size_t toff = (size_t)(n0 / 8 + wave) * 1024 + (size_t)mrow * 8
                    + (size_t)((tid & 1) << 2);

  const f32x4 b1r = *(const f32x4*)(b1f + c0);
  const f32x4 b2r = *(const f32x4*)(b2f + c0);

  // phase-1 wait: lanes 0..15 poll the 16 A-operand producers; lane 16 polls
  // chunk-2 (covers the hoisted fp32 prev read).
  const int p1pc = 16 * wave + l15 - 2;
  const bool p1needA = (lane < 16) && (p1pc >= 0);
  const bool p1needB = (lane == 16) && (chunk >= 2);
  const unsigned* p1fp =
      p1needA ? (sgen + p1pc * 16)
              : (sgen + (chunk >= 2 ? chunk - 2 : 0) * 16);
  const unsigned* p2fp = hgen + (16 * wave + l15) * 16;

  short8 xa[8], xb[8], xc[8], xd[8];   // 4-deep in-flight operand blocks

#pragma unroll 1
  for (int t = 0; t < NSTEPS; ++t) {
    const float* SfOld = (t & 1) ? Sf1 : Sf0;
    float*       SfNew = (t & 1) ? Sf0 : Sf1;
    const short* SbOld = (t & 1) ? Sb1 : Sb0;
    short*       SbNew = (t & 1) ? Sb0 : Sb1;

    // ================= phase 1: u = s_in @ W1^T ; h = |u + b1| =================
    f32x4 a00{}, a01{}, a10{}, a11{};
    f32x4 prevv;
    if (t == 0) {
      prevv = (c0 < 64) ? *(const f32x4*)(inp + (size_t)mrow * 64 + c0)
                        : f32x4{0.f, 0.f, 0.f, 0.f};
      if (kb == 0) {
        const float* q0_ = inp + (size_t)m0 * 64 + q8;
        const float* q1_ = inp + (size_t)m1 * 64 + q8;
        short8 x0 = pack8(*(const f32x4*)q0_, *(const f32x4*)(q0_ + 4));
        short8 x1 = pack8(*(const f32x4*)q1_, *(const f32x4*)(q1_ + 4));
        short8 x2 = pack8(*(const f32x4*)(q0_ + 32), *(const f32x4*)(q0_ + 36));
        short8 x3 = pack8(*(const f32x4*)(q1_ + 32), *(const f32x4*)(q1_ + 36));
        a00 = __builtin_amdgcn_mfma_f32_16x16x32_bf16(x0, B1[0][0], a00, 0, 0, 0);
        a01 = __builtin_amdgcn_mfma_f32_16x16x32_bf16(x0, B1[0][1], a01, 0, 0, 0);
        a10 = __builtin_amdgcn_mfma_f32_16x16x32_bf16(x1, B1[0][0], a10, 0, 0, 0);
        a11 = __builtin_amdgcn_mfma_f32_16x16x32_bf16(x1, B1[0][1], a11, 0, 0, 0);
        a00 = __builtin_amdgcn_mfma_f32_16x16x32_bf16(x2, B1[1][0], a00, 0, 0, 0);
        a01 = __builtin_amdgcn_mfma_f32_16x16x32_bf16(x2, B1[1][1], a01, 0, 0, 0);
        a10 = __builtin_amdgcn_mfma_f32_16x16x32_bf16(x3, B1[1][0], a10, 0, 0, 0);
        a11 = __builtin_amdgcn_mfma_f32_16x16x32_bf16(x3, B1[1][1], a11, 0, 0, 0);
      }
    } else {
      {  // one sticky wait for all of this wave's producers (before any issue)
        const unsigned tgt = (unsigned)t;
        bool pend = p1needA || p1needB;
        for (;;) {
          if (pend && ald32(p1fp) >= tgt) pend = false;
          if (__ballot(pend) == 0ull) break;
        }
      }
      if (chunk < 2) {
        prevv = *(const f32x4*)(inp + ((size_t)t * NB + mrow) * 64 + c0);
        P1ISSUE(0, xa); P1ISSUE(1, xb); P1ISSUE(2, xc); P1ISSUE(3, xd);
        VMW(24); P1MFMA(0, xa);
        VMW(16); P1MFMA(1, xb);
        VMW(8);  P1MFMA(2, xc);
        VMW(0);  P1MFMA(3, xd);
      } else {
        P1ISSUE(0, xa); P1ISSUE(1, xb); P1ISSUE(2, xc); P1ISSUE(3, xd);
        // hoisted epilogue prev; producer chunk-2 is same-XCD under verdict=1
        if (locPrev) {
          asm volatile("global_load_dwordx4 %0, %1, off sc0"
                       : "=&v"(prevv) : "v"(SfOld + toff - 8192));
        } else {
          LLCLD(prevv, (SfOld + toff - 8192));
        }
        VMW(25); P1MFMA(0, xa);
        VMW(17); P1MFMA(1, xb);
        VMW(9);  P1MFMA(2, xc);
        VMW(1);  P1MFMA(3, xd);
      }
    }
#pragma unroll
    for (int r = 0; r < 4; ++r) {            // ridx = mt*8 + nt*4 + r
      red[wave][r][lane]      = a00[r];
      red[wave][4 + r][lane]  = a01[r];
      red[wave][8 + r][lane]  = a10[r];
      red[wave][12 + r][lane] = a11[r];
    }
    __syncthreads();
    {
      short4v hv;
#pragma unroll
      for (int j = 0; j < 4; ++j) {
        const int nn   = nl + j;
        const int lidx = ((ml >> 2) & 3) * 16 + (nn & 15);
        const int ridx = (ml >> 4) * 8 + (nn >> 4) * 4 + (ml & 3);
        float s = red[0][ridx][lidx] + red[1][ridx][lidx]
                + red[2][ridx][lidx] + red[3][ridx][lidx];
        s += b1r[j];
        hv[j] = f2bf(fabsf(s));
      }
      union { short4v s; u64 u; } hu; hu.s = hv;
      ast64(hb + toff, hu.u);   // single sc1 write-through copy (R16 path)
    }
    __syncthreads();   // all 4 waves' stores drained (vmcnt0) before signal
    if (tid == 0)
      __hip_atomic_store(hgen + chunk * 16, (unsigned)t + 1,
                         __ATOMIC_RELAXED, __HIP_MEMORY_SCOPE_AGENT);

    // ================= phase 2: g = h @ W2^T ; state update =================
    f32x4 c00{}, c01{}, c10{}, c11{};
    {
      {  // one sticky wait for this wave's 16 h-producers
        const unsigned tgt = (unsigned)t + 1;
        bool pend = (lane < 16);
        for (;;) {
          if (pend && ald32(p2fp) >= tgt) pend = false;
          if (__ballot(pend) == 0ull) break;
        }
      }
      P2ISSUE(0, xa); P2ISSUE(1, xb); P2ISSUE(2, xc); P2ISSUE(3, xd);
      VMW(24); P2MFMA(0, xa);
      VMW(16); P2MFMA(1, xb);
      VMW(8);  P2MFMA(2, xc);
      VMW(0);  P2MFMA(3, xd);
    }
#pragma unroll
    for (int r = 0; r < 4; ++r) {
      red[wave][r][lane]      = c00[r];
      red[wave][4 + r][lane]  = c01[r];
      red[wave][8 + r][lane]  = c10[r];
      red[wave][12 + r][lane] = c11[r];
    }
    __syncthreads();
    if (t < NSTEPS - 1) {
      if (n0 < SS) {   // cols >= SS are dropped by the shift (except final step)
        f32x4 gv;
#pragma unroll
        for (int j = 0; j < 4; ++j) {
          const int nn   = nl + j;
          const int lidx = ((ml >> 2) & 3) * 16 + (nn & 15);
          const int ridx = (ml >> 4) * 8 + (nn >> 4) * 4 + (ml & 3);
          gv[j] = red[0][ridx][lidx] + red[1][ridx][lidx]
                + red[2][ridx][lidx] + red[3][ridx][lidx] + b2r[j];
        }
        f32x4 sv; short4v sb;
#pragma unroll
        for (int j = 0; j < 4; ++j) {
          float vv = 0.9f * prevv[j] + 0.1f * gv[j];
          sv[j] = vv; sb[j] = f2bf(vv);
        }
        union { f32x4 f; u64 u[2]; } sfu; sfu.f = sv;
        float* pf = SfNew + toff;
        ast64(pf, sfu.u[0]);
        ast64(pf + 2, sfu.u[1]);
        union { short4v s; u64 u; } sbu; sbu.s = sb;
        ast64(SbNew + toff, sbu.u);        // single sc1 copy
      }
      __syncthreads();   // all 4 waves' S stores drained before signal
      if (tid == 0 && chunk < 62)
        __hip_atomic_store(sgen + chunk * 16, (unsigned)t + 1,
                           __ATOMIC_RELAXED, __HIP_MEMORY_SCOPE_AGENT);
    } else {
      // final step: out[m, :] = 0.9*s_in[m, 1984+o] + 0.1*(g+b2)[m, 1984+o]
      if (n0 >= SS) {
        f32x4 gv;
#pragma unroll
        for (int j = 0; j < 4; ++j) {
          const int nn   = nl + j;
          const int lidx = ((ml >> 2) & 3) * 16 + (nn & 15);
          const int ridx = (ml >> 4) * 8 + (nn >> 4) * 4 + (ml & 3);
          gv[j] = red[0][ridx][lidx] + red[1][ridx][lidx]
                + red[2][ridx][lidx] + red[3][ridx][lidx] + b2r[j];
        }
        f32x4 ov;
#pragma unroll
        for (int j = 0; j < 4; ++j) ov[j] = 0.9f * prevv[j] + 0.1f * gv[j];
        *(f32x4*)(out + (size_t)mrow * 64 + (c0 - SS)) = ov;
      }
    }
  }
}

extern "C" void kernel_launch(void* const* d_in, const int* in_sizes, int n_in,
                              void* d_out, int out_size, void* d_ws, size_t ws_size,
                              hipStream_t stream)
{
  (void)in_sizes; (void)n_in; (void)out_size; (void)ws_size;
  const float* inp = (const float*)d_in[0];
  const float* W1  = (const float*)d_in[1];
  const float* b1  = (const float*)d_in[2];
  const float* W2  = (const float*)d_in[3];
  const float* b2  = (const float*)d_in[4];
  float* out = (float*)d_out;

  // zero flags + xcd table + verdict (ws re-poisoned before every launch)
  hipMemsetAsync(d_ws, 0, 34048, stream);
  resrnn_kernel<<<dim3(256), dim3(256), 0, stream>>>(
      inp, W1, b1, W2, b2, out, (unsigned char*)d_ws);
}